// Round 1
// baseline (470.768 us; speedup 1.0000x reference)
//
#include <hip/hip_runtime.h>
#include <math.h>

// Histogram2D: 2D Gaussian-smoothed histogram via erf CDF differences.
// N=500k points (D=6, use dims 0,1), 128x128 bins, bw = bin width.
// Key: erf saturates in f32 beyond ~5.8*dx from the point, so each point
// touches only a 12x12 bin window -> sparse scatter instead of dense GEMM.

#define NBINS   128
#define NSPAN   12            // bins per axis with non-negligible weight
#define THREADS 256
#define NBLOCKS 512           // 2 blocks/CU (64.5 KiB LDS each)

__global__ __launch_bounds__(THREADS, 2) void hist_accum_kernel(
    const float* __restrict__ x,
    const float* __restrict__ edges_x,
    const float* __restrict__ edges_y,
    float* __restrict__ gacc,
    int n)
{
    __shared__ float sh[NBINS * NBINS];      // 64 KiB private histogram
    __shared__ float sex[NBINS + 1];
    __shared__ float sey[NBINS + 1];

    const int tid = threadIdx.x;
    for (int i = tid; i < NBINS * NBINS; i += THREADS) sh[i] = 0.0f;
    if (tid <= NBINS) { sex[tid] = edges_x[tid]; sey[tid] = edges_y[tid]; }
    __syncthreads();

    const float e0x = sex[0];
    const float e0y = sey[0];
    const float dxw = sex[1] - e0x;
    const float dyw = sey[1] - e0y;
    const float inv_dx = 1.0f / dxw;
    const float inv_dy = 1.0f / dyw;
    // 1/(bw*sqrt(2)) with bw = BANDWIDTH * bin_width, BANDWIDTH = 1
    const float inv_bwx = inv_dx * 0.7071067811865476f;
    const float inv_bwy = inv_dy * 0.7071067811865476f;

    const int stride = gridDim.x * blockDim.x;
    for (int p = blockIdx.x * blockDim.x + tid; p < n; p += stride) {
        const float2 uv = *(const float2*)(x + (size_t)p * 6);
        const float u = uv.x, v = uv.y;

        const int cx = (int)floorf((u - e0x) * inv_dx);
        const int cy = (int)floorf((v - e0y) * inv_dy);
        int bx = cx - 5; bx = bx < 0 ? 0 : (bx > NBINS - NSPAN ? NBINS - NSPAN : bx);
        int by = cy - 5; by = by < 0 ? 0 : (by > NBINS - NSPAN ? NBINS - NSPAN : by);

        float wx[NSPAN], wy[NSPAN];
        float zx = erff((sex[bx] - u) * inv_bwx);
        float zy = erff((sey[by] - v) * inv_bwy);
        #pragma unroll
        for (int k = 0; k < NSPAN; ++k) {
            const float zx1 = erff((sex[bx + k + 1] - u) * inv_bwx);
            const float zy1 = erff((sey[by + k + 1] - v) * inv_bwy);
            wx[k] = 0.5f * (zx1 - zx);
            wy[k] = 0.5f * (zy1 - zy);
            zx = zx1; zy = zy1;
        }

        #pragma unroll
        for (int i = 0; i < NSPAN; ++i) {
            float* row = sh + (bx + i) * NBINS + by;
            const float wxi = wx[i];
            #pragma unroll
            for (int j = 0; j < NSPAN; ++j) {
                unsafeAtomicAdd(&row[j], wxi * wy[j]);   // ds_add_f32
            }
        }
    }
    __syncthreads();

    // flush private histogram to global accumulator
    for (int i = tid; i < NBINS * NBINS; i += THREADS) {
        const float s = sh[i];
        if (s != 0.0f) unsafeAtomicAdd(&gacc[i], s);
    }
}

__global__ void reduce_kernel(const float* __restrict__ gacc,
                              float* __restrict__ total)
{
    float acc = 0.0f;
    for (int i = threadIdx.x; i < NBINS * NBINS; i += 256) acc += gacc[i];
    #pragma unroll
    for (int off = 32; off > 0; off >>= 1) acc += __shfl_down(acc, off, 64);
    __shared__ float ws[4];
    if ((threadIdx.x & 63) == 0) ws[threadIdx.x >> 6] = acc;
    __syncthreads();
    if (threadIdx.x == 0) *total = ws[0] + ws[1] + ws[2] + ws[3];
}

__global__ void scale_kernel(const float* __restrict__ gacc,
                             const float* __restrict__ total,
                             const float* __restrict__ edges_x,
                             const float* __restrict__ edges_y,
                             float* __restrict__ out)
{
    const float dxw = edges_x[1] - edges_x[0];
    const float dyw = edges_y[1] - edges_y[0];
    const float scale = 1.0f / (*total * dxw * dyw);
    const int i = blockIdx.x * blockDim.x + threadIdx.x;
    if (i < NBINS * NBINS) out[i] = gacc[i] * scale;
}

extern "C" void kernel_launch(void* const* d_in, const int* in_sizes, int n_in,
                              void* d_out, int out_size, void* d_ws, size_t ws_size,
                              hipStream_t stream)
{
    const float* x  = (const float*)d_in[0];
    const float* ex = (const float*)d_in[1];
    const float* ey = (const float*)d_in[2];
    float* out = (float*)d_out;

    float* gacc  = (float*)d_ws;                 // 16384 floats
    float* total = gacc + NBINS * NBINS;         // 1 float (written by reduce)
    const int n = in_sizes[0] / 6;

    hipMemsetAsync(gacc, 0, NBINS * NBINS * sizeof(float), stream);
    hist_accum_kernel<<<NBLOCKS, THREADS, 0, stream>>>(x, ex, ey, gacc, n);
    reduce_kernel<<<1, 256, 0, stream>>>(gacc, total);
    scale_kernel<<<(NBINS * NBINS + 255) / 256, 256, 0, stream>>>(gacc, total, ex, ey, out);
}

// Round 2
// 467.954 us; speedup vs baseline: 1.0060x; 1.0060x over previous
//
#include <hip/hip_runtime.h>
#include <math.h>

// Histogram2D: 2D Gaussian-smoothed histogram via erf CDF differences.
// N=500k points (D=6, use dims 0,1), 128x128 bins, bw = bin width.
// erf saturates in f32 beyond ~5.8*dx, so each point touches only a 12x12
// bin window -> sparse scatter into per-block LDS histograms.
// R1 lesson: 512-way same-address global atomic flush cost ~380us.
// Fix: per-block partials in d_ws + two-level contention-free reduction.

#define NBINS   128
#define NB2     (NBINS * NBINS)
#define NSPAN   12
#define THREADS 256
#define NBLOCKS 512           // 2 blocks/CU (64.5 KiB LDS each)
#define NGRP    16            // first-level reduction groups
#define PPG     (NBLOCKS / NGRP)   // partials per group = 32

__global__ __launch_bounds__(THREADS, 2) void hist_accum_kernel(
    const float* __restrict__ x,
    const float* __restrict__ edges_x,
    const float* __restrict__ edges_y,
    float* __restrict__ dst,        // partials base (or gacc in atomic mode)
    int n, int atomic_mode)
{
    __shared__ float sh[NB2];       // 64 KiB private histogram
    __shared__ float sex[NBINS + 1];
    __shared__ float sey[NBINS + 1];

    const int tid = threadIdx.x;
    for (int i = tid; i < NB2; i += THREADS) sh[i] = 0.0f;
    if (tid <= NBINS) { sex[tid] = edges_x[tid]; sey[tid] = edges_y[tid]; }
    __syncthreads();

    const float e0x = sex[0];
    const float e0y = sey[0];
    const float dxw = sex[1] - e0x;
    const float dyw = sey[1] - e0y;
    const float inv_dx = 1.0f / dxw;
    const float inv_dy = 1.0f / dyw;
    const float inv_bwx = inv_dx * 0.7071067811865476f;  // 1/(bw*sqrt2), bw=dx
    const float inv_bwy = inv_dy * 0.7071067811865476f;

    const int stride = gridDim.x * blockDim.x;
    for (int p = blockIdx.x * blockDim.x + tid; p < n; p += stride) {
        const float2 uv = *(const float2*)(x + (size_t)p * 6);
        const float u = uv.x, v = uv.y;

        const int cx = (int)floorf((u - e0x) * inv_dx);
        const int cy = (int)floorf((v - e0y) * inv_dy);
        int bx = cx - 5; bx = bx < 0 ? 0 : (bx > NBINS - NSPAN ? NBINS - NSPAN : bx);
        int by = cy - 5; by = by < 0 ? 0 : (by > NBINS - NSPAN ? NBINS - NSPAN : by);

        float wx[NSPAN], wy[NSPAN];
        float zx = erff((sex[bx] - u) * inv_bwx);
        float zy = erff((sey[by] - v) * inv_bwy);
        #pragma unroll
        for (int k = 0; k < NSPAN; ++k) {
            const float zx1 = erff((sex[bx + k + 1] - u) * inv_bwx);
            const float zy1 = erff((sey[by + k + 1] - v) * inv_bwy);
            wx[k] = 0.5f * (zx1 - zx);
            wy[k] = 0.5f * (zy1 - zy);
            zx = zx1; zy = zy1;
        }

        #pragma unroll
        for (int i = 0; i < NSPAN; ++i) {
            float* row = sh + (bx + i) * NBINS + by;
            const float wxi = wx[i];
            #pragma unroll
            for (int j = 0; j < NSPAN; ++j) {
                unsafeAtomicAdd(&row[j], wxi * wy[j]);   // ds_add_f32
            }
        }
    }
    __syncthreads();

    if (atomic_mode) {
        // fallback: contended but correct
        for (int i = tid; i < NB2; i += THREADS) {
            const float s = sh[i];
            if (s != 0.0f) unsafeAtomicAdd(&dst[i], s);
        }
    } else {
        // contention-free: private slice, float4 coalesced stores
        float* my = dst + (size_t)blockIdx.x * NB2;
        for (int i = tid * 4; i < NB2; i += THREADS * 4) {
            *(float4*)(my + i) = *(const float4*)(sh + i);
        }
    }
}

// level 1: 512 partials -> 16, grid (NB2/256, NGRP)
__global__ void reduceA_kernel(const float* __restrict__ partials,
                               float* __restrict__ partial2)
{
    const int bin = blockIdx.x * blockDim.x + threadIdx.x;
    const int g = blockIdx.y;
    const float* p = partials + (size_t)g * PPG * NB2 + bin;
    float s = 0.0f;
    #pragma unroll
    for (int k = 0; k < PPG; ++k) s += p[(size_t)k * NB2];
    partial2[g * NB2 + bin] = s;
}

// level 2: 16 -> 1, also accumulate grand total
__global__ void reduceB_kernel(const float* __restrict__ partial2,
                               float* __restrict__ gacc,
                               float* __restrict__ total)
{
    const int bin = blockIdx.x * blockDim.x + threadIdx.x;
    float s = 0.0f;
    #pragma unroll
    for (int g = 0; g < NGRP; ++g) s += partial2[g * NB2 + bin];
    gacc[bin] = s;

    float acc = s;
    #pragma unroll
    for (int off = 32; off > 0; off >>= 1) acc += __shfl_down(acc, off, 64);
    __shared__ float ws[4];
    if ((threadIdx.x & 63) == 0) ws[threadIdx.x >> 6] = acc;
    __syncthreads();
    if (threadIdx.x == 0) unsafeAtomicAdd(total, ws[0] + ws[1] + ws[2] + ws[3]);
}

// fallback single-block reduce (atomic path)
__global__ void reduce_kernel(const float* __restrict__ gacc,
                              float* __restrict__ total)
{
    float acc = 0.0f;
    for (int i = threadIdx.x; i < NB2; i += 256) acc += gacc[i];
    #pragma unroll
    for (int off = 32; off > 0; off >>= 1) acc += __shfl_down(acc, off, 64);
    __shared__ float ws[4];
    if ((threadIdx.x & 63) == 0) ws[threadIdx.x >> 6] = acc;
    __syncthreads();
    if (threadIdx.x == 0) *total = ws[0] + ws[1] + ws[2] + ws[3];
}

__global__ void scale_kernel(const float* __restrict__ gacc,
                             const float* __restrict__ total,
                             const float* __restrict__ edges_x,
                             const float* __restrict__ edges_y,
                             float* __restrict__ out)
{
    const float dxw = edges_x[1] - edges_x[0];
    const float dyw = edges_y[1] - edges_y[0];
    const float scale = 1.0f / (*total * dxw * dyw);
    const int i = blockIdx.x * blockDim.x + threadIdx.x;
    if (i < NB2) out[i] = gacc[i] * scale;
}

extern "C" void kernel_launch(void* const* d_in, const int* in_sizes, int n_in,
                              void* d_out, int out_size, void* d_ws, size_t ws_size,
                              hipStream_t stream)
{
    const float* x  = (const float*)d_in[0];
    const float* ex = (const float*)d_in[1];
    const float* ey = (const float*)d_in[2];
    float* out = (float*)d_out;
    const int n = in_sizes[0] / 6;

    const size_t need = ((size_t)NBLOCKS + NGRP + 1) * NB2 * sizeof(float) + 256;

    if (ws_size >= need) {
        float* partials = (float*)d_ws;                       // 512 * 16384
        float* partial2 = partials + (size_t)NBLOCKS * NB2;   // 16 * 16384
        float* gacc     = partial2 + (size_t)NGRP * NB2;      // 16384
        float* total    = gacc + NB2;                         // 1

        hipMemsetAsync(total, 0, sizeof(float), stream);
        hist_accum_kernel<<<NBLOCKS, THREADS, 0, stream>>>(x, ex, ey, partials, n, 0);
        reduceA_kernel<<<dim3(NB2 / 256, NGRP), 256, 0, stream>>>(partials, partial2);
        reduceB_kernel<<<NB2 / 256, 256, 0, stream>>>(partial2, gacc, total);
        scale_kernel<<<NB2 / 256, 256, 0, stream>>>(gacc, total, ex, ey, out);
    } else {
        float* gacc  = (float*)d_ws;
        float* total = gacc + NB2;
        hipMemsetAsync(gacc, 0, (NB2 + 1) * sizeof(float), stream);
        hist_accum_kernel<<<NBLOCKS, THREADS, 0, stream>>>(x, ex, ey, gacc, n, 1);
        reduce_kernel<<<1, 256, 0, stream>>>(gacc, total);
        scale_kernel<<<NB2 / 256, 256, 0, stream>>>(gacc, total, ex, ey, out);
    }
}

// Round 3
// 108.007 us; speedup vs baseline: 4.3587x; 4.3326x over previous
//
#include <hip/hip_runtime.h>
#include <math.h>

// Histogram2D as MFMA GEMM: hist[i][j] = sum_n wx[n][i]*wy[n][j].
// erf saturates beyond ~5.8 bins -> each point has 12 nonzero weights/axis.
// R2 lesson: per-point LDS f32 atomics serialize per-lane (~950k cyc/CU);
// scatter plain bf16 weights into MFMA-fragment-swizzled LDS (one writer
// per slot, no atomics), then v_mfma_f32_16x16x32_bf16 with register
// 128x128 f32 accumulators per block. Partials -> 2-level reduction.

#define NBINS   128
#define NB2     (NBINS * NBINS)
#define KC      128              // points per chunk
#define NK      (KC / 32)        // K-steps of 32 per chunk = 4
#define TILE_ST (NK * 512)       // bf16 elems per (tile) group = 2048
#define AX_ST   (8 * TILE_ST)    // bf16 elems per axis = 16384
#define THREADS 256
#define NBLOCKS 512              // 2 blocks/CU (64 KiB LDS each)
#define NGRP    16
#define PPG     (NBLOCKS / NGRP) // 32

typedef short  short8 __attribute__((ext_vector_type(8)));  // 8 bf16
typedef float  f32x4  __attribute__((ext_vector_type(4)));

__global__ __launch_bounds__(THREADS, 2) void hist_mfma_kernel(
    const float* __restrict__ x,
    const float* __restrict__ edges_x,
    const float* __restrict__ edges_y,
    float* __restrict__ partials,
    int n)
{
    // Fragment-swizzled staging: axis A (wx^T) then axis B (wy).
    // Element (bin b, point p): t=b>>4, r=b&15, s=p>>5, q=(p>>3)&3, j=p&7
    // offset = axis*AX_ST + t*TILE_ST + s*512 + q*128 + r*8 + j
    // -> wave b128 frag read at (tile,s): base + lane*8, stride-1, conflict-free.
    __shared__ __bf16 sh[2 * AX_ST];   // 64 KiB

    const int tid  = threadIdx.x;
    const int lane = tid & 63;
    const int wv   = tid >> 6;

    const float e0x = edges_x[0];
    const float dxw = edges_x[1] - e0x;
    const float e0y = edges_y[0];
    const float dyw = edges_y[1] - e0y;

    // scatter role: threads 0..127 axis x, 128..255 axis y; point = base + (tid&127)
    const int axis = tid >> 7;
    const int pl   = tid & 127;
    const float e0   = axis ? e0y : e0x;
    const float invd = 1.0f / (axis ? dyw : dxw);
    const float cc   = 0.7071067811865476f;   // 1/sqrt(2), since bw = bin width
    const int scat_base = axis * AX_ST + (pl >> 5) * 512 + ((pl >> 3) & 3) * 128 + (pl & 7);

    f32x4 acc[4][4];
    #pragma unroll
    for (int i = 0; i < 4; ++i)
        #pragma unroll
        for (int j = 0; j < 4; ++j)
            acc[i][j] = (f32x4){0.f, 0.f, 0.f, 0.f};

    const int rowQ = (wv >> 1) * 4;   // wave's 4x4 tile quadrant
    const int colQ = (wv & 1) * 4;

    const int nchunks = (n + KC - 1) / KC;
    for (int chunk = blockIdx.x; chunk < nchunks; chunk += gridDim.x) {
        const int base = chunk * KC;

        // zero staging (stride-1 b128 stores, conflict-free)
        float4* zp = (float4*)sh;
        #pragma unroll
        for (int i = 0; i < 16; ++i)
            zp[tid + i * THREADS] = (float4){0.f, 0.f, 0.f, 0.f};
        __syncthreads();

        const int p = base + pl;
        if (p < n) {
            const float u    = x[(size_t)p * 6 + axis];
            const float spos = (u - e0) * invd;            // position in bin units
            int b0 = (int)floorf(spos) - 5;
            b0 = b0 < 0 ? 0 : (b0 > NBINS - 12 ? NBINS - 12 : b0);
            // edges are linspace: arg_k = (b0 + k - spos)/sqrt(2)
            const float t0 = ((float)b0 - spos) * cc;
            float zprev = erff(t0);
            #pragma unroll
            for (int k = 0; k < 12; ++k) {
                const float zk  = erff(t0 + (float)(k + 1) * cc);
                const float wgt = 0.5f * (zk - zprev);
                zprev = zk;
                const int b = b0 + k;
                sh[scat_base + (b >> 4) * TILE_ST + (b & 15) * 8] = (__bf16)wgt;
            }
        }
        __syncthreads();

        #pragma unroll
        for (int s = 0; s < NK; ++s) {
            short8 av[4], bv[4];
            #pragma unroll
            for (int i = 0; i < 4; ++i)
                av[i] = *(short8*)&sh[(rowQ + i) * TILE_ST + s * 512 + lane * 8];
            #pragma unroll
            for (int j = 0; j < 4; ++j)
                bv[j] = *(short8*)&sh[AX_ST + (colQ + j) * TILE_ST + s * 512 + lane * 8];
            #pragma unroll
            for (int i = 0; i < 4; ++i)
                #pragma unroll
                for (int j = 0; j < 4; ++j)
                    acc[i][j] = __builtin_amdgcn_mfma_f32_16x16x32_bf16(
                        av[i], bv[j], acc[i][j], 0, 0, 0);
        }
        __syncthreads();
    }

    // epilogue: C/D layout col=lane&15, row=(lane>>4)*4+reg (m89/m91-verified)
    float* my = partials + (size_t)blockIdx.x * NB2;
    const int r0 = (lane >> 4) * 4;
    const int c0 = lane & 15;
    #pragma unroll
    for (int i = 0; i < 4; ++i)
        #pragma unroll
        for (int j = 0; j < 4; ++j)
            #pragma unroll
            for (int g = 0; g < 4; ++g) {
                const int row = (rowQ + i) * 16 + r0 + g;
                const int col = (colQ + j) * 16 + c0;
                my[row * NBINS + col] = acc[i][j][g];
            }
}

// level 1: 512 partials -> 16, float4-vectorized; grid (16, NGRP)
__global__ void reduceA_kernel(const float* __restrict__ partials,
                               float* __restrict__ partial2)
{
    const int bin4 = (blockIdx.x * 256 + threadIdx.x) * 4;
    const int g = blockIdx.y;
    const float4* p = (const float4*)(partials + (size_t)g * PPG * NB2 + bin4);
    float4 s = {0.f, 0.f, 0.f, 0.f};
    #pragma unroll
    for (int k = 0; k < PPG; ++k) {
        const float4 v = p[(size_t)k * (NB2 / 4)];
        s.x += v.x; s.y += v.y; s.z += v.z; s.w += v.w;
    }
    *(float4*)(partial2 + (size_t)g * NB2 + bin4) = s;
}

// level 2: 16 -> 1, plus grand total via one atomic per block
__global__ void reduceB_kernel(const float* __restrict__ partial2,
                               float* __restrict__ gacc,
                               float* __restrict__ total)
{
    const int bin = blockIdx.x * blockDim.x + threadIdx.x;
    float s = 0.0f;
    #pragma unroll
    for (int g = 0; g < NGRP; ++g) s += partial2[g * NB2 + bin];
    gacc[bin] = s;

    float acc = s;
    #pragma unroll
    for (int off = 32; off > 0; off >>= 1) acc += __shfl_down(acc, off, 64);
    __shared__ float ws[4];
    if ((threadIdx.x & 63) == 0) ws[threadIdx.x >> 6] = acc;
    __syncthreads();
    if (threadIdx.x == 0) unsafeAtomicAdd(total, ws[0] + ws[1] + ws[2] + ws[3]);
}

__global__ void scale_kernel(const float* __restrict__ gacc,
                             const float* __restrict__ total,
                             const float* __restrict__ edges_x,
                             const float* __restrict__ edges_y,
                             float* __restrict__ out)
{
    const float dxw = edges_x[1] - edges_x[0];
    const float dyw = edges_y[1] - edges_y[0];
    const float scale = 1.0f / (*total * dxw * dyw);
    const int i = blockIdx.x * blockDim.x + threadIdx.x;
    if (i < NB2) out[i] = gacc[i] * scale;
}

extern "C" void kernel_launch(void* const* d_in, const int* in_sizes, int n_in,
                              void* d_out, int out_size, void* d_ws, size_t ws_size,
                              hipStream_t stream)
{
    const float* x  = (const float*)d_in[0];
    const float* ex = (const float*)d_in[1];
    const float* ey = (const float*)d_in[2];
    float* out = (float*)d_out;
    const int n = in_sizes[0] / 6;

    float* partials = (float*)d_ws;                       // 512 * 16384
    float* partial2 = partials + (size_t)NBLOCKS * NB2;   // 16 * 16384
    float* gacc     = partial2 + (size_t)NGRP * NB2;      // 16384
    float* total    = gacc + NB2;                         // 1

    hipMemsetAsync(total, 0, sizeof(float), stream);
    hist_mfma_kernel<<<NBLOCKS, THREADS, 0, stream>>>(x, ex, ey, partials, n);
    reduceA_kernel<<<dim3(NB2 / 1024, NGRP), 256, 0, stream>>>(partials, partial2);
    reduceB_kernel<<<NB2 / 256, 256, 0, stream>>>(partial2, gacc, total);
    scale_kernel<<<NB2 / 256, 256, 0, stream>>>(gacc, total, ex, ey, out);
}

// Round 4
// 96.976 us; speedup vs baseline: 4.8545x; 1.1138x over previous
//
#include <hip/hip_runtime.h>
#include <math.h>

// Histogram2D as i8 MFMA GEMM: hist[i][j] = sum_n wx[n][i]*wy[n][j].
// Weights in [0, 0.383] -> fixed-point q = rint(w*320) (max 123 < 127),
// exact i32 accumulation; uniform quant error 1/640 per weight.
// erf window of 8 bins suffices: anything further is < 0.5 quant LSB.
// R3 lesson: ~42us of dur is the harness 0xAA poison of d_ws (fixed floor);
// hist kernel is LDS-pipe bound -> i8 halves staging bytes, KC=256 halves
// barriers per point. Layout puts each MFMA fragment at lane*16 stride-1.

#define NBINS   128
#define NB2     (NBINS * NBINS)
#define KC      256               // points per chunk (= THREADS)
#define NS      (KC / 64)         // K-steps of 64 -> 4
#define AX_B    32768             // bytes per axis staging: 128*256
#define THREADS 256
#define NBLOCKS 512               // 2 blocks/CU (64 KiB LDS each)
#define NGRP    16
#define PPG     (NBLOCKS / NGRP)  // 32
#define QSCALE  320.0f

typedef int i32x4 __attribute__((ext_vector_type(4)));

__global__ __launch_bounds__(THREADS, 2) void hist_mfma_kernel(
    const float* __restrict__ x,
    const float* __restrict__ edges_x,
    const float* __restrict__ edges_y,
    float* __restrict__ partials,
    int n)
{
    // Staging element (bin b, point p), per axis:
    //   off = (b>>4)*4096 + (p>>6)*1024 + ((p>>4)&3)*256 + (b&15)*16 + (p&15)
    // Frag read (tile t, kstep s, lane l): base + t*4096 + s*1024 + l*16
    // -> 16 contiguous bytes/lane, stride-1 across wave, conflict-free.
    __shared__ __align__(16) signed char sh[2 * AX_B];   // 64 KiB

    const int tid  = threadIdx.x;
    const int lane = tid & 63;
    const int wv   = tid >> 6;

    const float e0x = edges_x[0];
    const float dxw = edges_x[1] - e0x;
    const float e0y = edges_y[0];
    const float dyw = edges_y[1] - e0y;
    const float inv_dx = 1.0f / dxw;
    const float inv_dy = 1.0f / dyw;
    const float cc = 0.7071067811865476f;   // 1/sqrt(2); bw = bin width

    // point-local scatter base (p = tid within chunk)
    const int pbase = (tid >> 6) * 1024 + ((tid >> 4) & 3) * 256 + (tid & 15);

    i32x4 acc[4][4];
    #pragma unroll
    for (int i = 0; i < 4; ++i)
        #pragma unroll
        for (int j = 0; j < 4; ++j)
            acc[i][j] = (i32x4){0, 0, 0, 0};

    const int rowQ = (wv >> 1) * 4;   // wave's 4x4 quadrant of 16x16 tiles
    const int colQ = (wv & 1) * 4;

    const int nchunks = (n + KC - 1) / KC;
    for (int chunk = blockIdx.x; chunk < nchunks; chunk += gridDim.x) {
        const int p = chunk * KC + tid;

        // issue x load early; zero loop below is independent
        float u = 1e30f, v = 1e30f;
        if (p < n) {
            const float2 uv = *(const float2*)(x + (size_t)p * 6);
            u = uv.x; v = uv.y;
        }

        // zero staging: 4096 float4 stores, stride-1
        float4* zp = (float4*)sh;
        #pragma unroll
        for (int i = 0; i < 16; ++i)
            zp[tid + i * THREADS] = (float4){0.f, 0.f, 0.f, 0.f};
        __syncthreads();

        // scatter both axes for point p (8 bins each)
        #pragma unroll
        for (int a = 0; a < 2; ++a) {
            const float uu   = a ? v : u;
            const float e0   = a ? e0y : e0x;
            const float invd = a ? inv_dy : inv_dx;
            const float spos = (uu - e0) * invd;
            int b0 = (int)floorf(spos + 0.5f) - 4;
            b0 = b0 < 0 ? 0 : (b0 > NBINS - 8 ? NBINS - 8 : b0);
            const float t0 = ((float)b0 - spos) * cc;
            float zprev = erff(t0);
            signed char* dst = sh + a * AX_B + pbase;
            #pragma unroll
            for (int k = 0; k < 8; ++k) {
                const float zk = erff(t0 + (float)(k + 1) * cc);
                const float w  = 0.5f * (zk - zprev);
                zprev = zk;
                const int q = (int)rintf(w * QSCALE);
                const int b = b0 + k;
                dst[(b >> 4) * 4096 + (b & 15) * 16] = (signed char)q;
            }
        }
        __syncthreads();

        #pragma unroll
        for (int s = 0; s < NS; ++s) {
            i32x4 av[4], bv[4];
            #pragma unroll
            for (int i = 0; i < 4; ++i)
                av[i] = *(const i32x4*)(sh + (rowQ + i) * 4096 + s * 1024 + lane * 16);
            #pragma unroll
            for (int j = 0; j < 4; ++j)
                bv[j] = *(const i32x4*)(sh + AX_B + (colQ + j) * 4096 + s * 1024 + lane * 16);
            #pragma unroll
            for (int i = 0; i < 4; ++i)
                #pragma unroll
                for (int j = 0; j < 4; ++j)
                    acc[i][j] = __builtin_amdgcn_mfma_i32_16x16x64_i8(
                        av[i], bv[j], acc[i][j], 0, 0, 0);
        }
        __syncthreads();
    }

    // epilogue: C/D layout col=lane&15, row=(lane>>4)*4+reg (shape-determined)
    const float qs = 1.0f / (QSCALE * QSCALE);
    float* my = partials + (size_t)blockIdx.x * NB2;
    const int r0 = (lane >> 4) * 4;
    const int c0 = lane & 15;
    #pragma unroll
    for (int i = 0; i < 4; ++i)
        #pragma unroll
        for (int j = 0; j < 4; ++j)
            #pragma unroll
            for (int g = 0; g < 4; ++g) {
                const int row = (rowQ + i) * 16 + r0 + g;
                const int col = (colQ + j) * 16 + c0;
                my[row * NBINS + col] = (float)acc[i][j][g] * qs;
            }
}

// level 1: 512 partials -> 16, float4-vectorized; grid (16, NGRP)
__global__ void reduceA_kernel(const float* __restrict__ partials,
                               float* __restrict__ partial2)
{
    const int bin4 = (blockIdx.x * 256 + threadIdx.x) * 4;
    const int g = blockIdx.y;
    const float4* p = (const float4*)(partials + (size_t)g * PPG * NB2 + bin4);
    float4 s = {0.f, 0.f, 0.f, 0.f};
    #pragma unroll
    for (int k = 0; k < PPG; ++k) {
        const float4 v = p[(size_t)k * (NB2 / 4)];
        s.x += v.x; s.y += v.y; s.z += v.z; s.w += v.w;
    }
    *(float4*)(partial2 + (size_t)g * NB2 + bin4) = s;
}

// level 2: 16 -> 1, plus grand total via one atomic per block
__global__ void reduceB_kernel(const float* __restrict__ partial2,
                               float* __restrict__ gacc,
                               float* __restrict__ total)
{
    const int bin = blockIdx.x * blockDim.x + threadIdx.x;
    float s = 0.0f;
    #pragma unroll
    for (int g = 0; g < NGRP; ++g) s += partial2[g * NB2 + bin];
    gacc[bin] = s;

    float acc = s;
    #pragma unroll
    for (int off = 32; off > 0; off >>= 1) acc += __shfl_down(acc, off, 64);
    __shared__ float ws[4];
    if ((threadIdx.x & 63) == 0) ws[threadIdx.x >> 6] = acc;
    __syncthreads();
    if (threadIdx.x == 0) unsafeAtomicAdd(total, ws[0] + ws[1] + ws[2] + ws[3]);
}

__global__ void scale_kernel(const float* __restrict__ gacc,
                             const float* __restrict__ total,
                             const float* __restrict__ edges_x,
                             const float* __restrict__ edges_y,
                             float* __restrict__ out)
{
    const float dxw = edges_x[1] - edges_x[0];
    const float dyw = edges_y[1] - edges_y[0];
    const float scale = 1.0f / (*total * dxw * dyw);
    const int i = blockIdx.x * blockDim.x + threadIdx.x;
    if (i < NB2) out[i] = gacc[i] * scale;
}

extern "C" void kernel_launch(void* const* d_in, const int* in_sizes, int n_in,
                              void* d_out, int out_size, void* d_ws, size_t ws_size,
                              hipStream_t stream)
{
    const float* x  = (const float*)d_in[0];
    const float* ex = (const float*)d_in[1];
    const float* ey = (const float*)d_in[2];
    float* out = (float*)d_out;
    const int n = in_sizes[0] / 6;

    float* partials = (float*)d_ws;                       // 512 * 16384
    float* partial2 = partials + (size_t)NBLOCKS * NB2;   // 16 * 16384
    float* gacc     = partial2 + (size_t)NGRP * NB2;      // 16384
    float* total    = gacc + NB2;                         // 1

    hipMemsetAsync(total, 0, sizeof(float), stream);
    hist_mfma_kernel<<<NBLOCKS, THREADS, 0, stream>>>(x, ex, ey, partials, n);
    reduceA_kernel<<<dim3(NB2 / 1024, NGRP), 256, 0, stream>>>(partials, partial2);
    reduceB_kernel<<<NB2 / 256, 256, 0, stream>>>(partial2, gacc, total);
    scale_kernel<<<NB2 / 256, 256, 0, stream>>>(gacc, total, ex, ey, out);
}

// Round 5
// 89.168 us; speedup vs baseline: 5.2795x; 1.0876x over previous
//
#include <hip/hip_runtime.h>
#include <math.h>

// Histogram2D as i8 MFMA GEMM: hist[i][j] = sum_n wx[n][i]*wy[n][j].
// q = rint(w*320) (max 123 < 127), exact i32 accumulation; 8-bin window
// (further bins < 0.5 quant LSB). ~42us of dur is the harness 0xAA poison
// of the 256MiB d_ws (fixed floor).
// R4 lesson: hist is barrier/latency-bound (3 barriers/chunk at only
// 8 waves/CU), not LDS-throughput-bound. R5: 512-thread blocks (16
// waves/CU), waves split K per chunk, axis-split scatter (9 erf/thread,
// computed pre-barrier), i32 wave-pair merge in epilogue, fused tail.

#define NBINS   128
#define NB2     (NBINS * NBINS)
#define KC      256               // points per chunk
#define AX_B    32768             // bytes per axis staging: 128*256
#define THREADS 512
#define NBLOCKS 512               // 2 blocks/CU (64 KiB LDS each)
#define NGRP    16
#define PPG     (NBLOCKS / NGRP)  // 32
#define QSCALE  320.0f

typedef int i32x4 __attribute__((ext_vector_type(4)));

__global__ __launch_bounds__(THREADS, 4) void hist_mfma_kernel(
    const float* __restrict__ x,
    const float* __restrict__ edges_x,
    const float* __restrict__ edges_y,
    float* __restrict__ partials,
    float* __restrict__ btot,
    int n)
{
    // Staging element (bin b, point p), per axis:
    //   off = (b>>4)*4096 + (p>>6)*1024 + ((p>>4)&3)*256 + (b&15)*16 + (p&15)
    // Frag read (tile t, kstep s, lane l): t*4096 + s*1024 + l*16 ->
    // 16 contiguous bytes/lane, conflict-free; matches i8 A-layout
    // A[m=lane&15][k=(lane>>4)*16+j] (numerically verified R3/R4).
    __shared__ __align__(16) signed char sh[2 * AX_B];   // 64 KiB
    __shared__ int xw[8];

    const int tid  = threadIdx.x;
    const int lane = tid & 63;
    const int wv   = tid >> 6;        // 0..7

    const float e0x = edges_x[0];
    const float dxw = edges_x[1] - e0x;
    const float e0y = edges_y[0];
    const float dyw = edges_y[1] - e0y;

    // scatter role: threads 0..255 axis x, 256..511 axis y, point = pl
    const int axis = tid >> 8;
    const int pl   = tid & 255;
    const float e0   = axis ? e0y : e0x;
    const float invd = 1.0f / (axis ? dyw : dxw);
    const float cc   = 0.7071067811865476f;   // 1/sqrt(2); bw = bin width
    signed char* const sdst =
        sh + axis * AX_B + (pl >> 6) * 1024 + ((pl >> 4) & 3) * 256 + (pl & 15);

    i32x4 acc[4][4];
    #pragma unroll
    for (int i = 0; i < 4; ++i)
        #pragma unroll
        for (int j = 0; j < 4; ++j)
            acc[i][j] = (i32x4){0, 0, 0, 0};

    const int rowQ = ((wv >> 1) & 1) * 4;  // 4x4 tile quadrant (16x16 tiles)
    const int colQ = (wv & 1) * 4;
    const int ks0  = (wv >> 2) * 2;        // K-split: waves 0-3 ksteps {0,1}, 4-7 {2,3}

    const int nchunks = (n + KC - 1) / KC;
    for (int chunk = blockIdx.x; chunk < nchunks; chunk += gridDim.x) {
        const int p = chunk * KC + pl;
        float u = 1e30f;
        if (p < n) u = x[(size_t)p * 6 + axis];

        // q-bytes computed BEFORE the barrier region (erf off critical path)
        const float spos = (u - e0) * invd;
        int b0 = (int)floorf(spos + 0.5f) - 4;
        b0 = b0 < 0 ? 0 : (b0 > NBINS - 8 ? NBINS - 8 : b0);
        const float t0 = ((float)b0 - spos) * cc;
        float z[9];
        #pragma unroll
        for (int k = 0; k < 9; ++k) z[k] = erff(t0 + (float)k * cc);
        signed char qv[8];
        #pragma unroll
        for (int k = 0; k < 8; ++k)
            qv[k] = (signed char)(int)rintf(0.5f * (z[k + 1] - z[k]) * QSCALE);

        // zero staging: 512 thr x 8 float4
        float4* zp = (float4*)sh;
        #pragma unroll
        for (int i = 0; i < 8; ++i)
            zp[tid + i * THREADS] = (float4){0.f, 0.f, 0.f, 0.f};
        __syncthreads();

        #pragma unroll
        for (int k = 0; k < 8; ++k) {
            const int b = b0 + k;
            sdst[(b >> 4) * 4096 + (b & 15) * 16] = qv[k];
        }
        __syncthreads();

        #pragma unroll
        for (int s = 0; s < 2; ++s) {
            const int ks = ks0 + s;
            i32x4 av[4], bv[4];
            #pragma unroll
            for (int i = 0; i < 4; ++i)
                av[i] = *(const i32x4*)(sh + (rowQ + i) * 4096 + ks * 1024 + lane * 16);
            #pragma unroll
            for (int j = 0; j < 4; ++j)
                bv[j] = *(const i32x4*)(sh + AX_B + (colQ + j) * 4096 + ks * 1024 + lane * 16);
            #pragma unroll
            for (int i = 0; i < 4; ++i)
                #pragma unroll
                for (int j = 0; j < 4; ++j)
                    acc[i][j] = __builtin_amdgcn_mfma_i32_16x16x64_i8(
                        av[i], bv[j], acc[i][j], 0, 0, 0);
        }
        __syncthreads();
    }

    // epilogue: merge K-split wave pairs (exact i32), then scale & store.
    // C/D layout col=lane&15, row=(lane>>4)*4+reg (shape-determined).
    if (wv >= 4) {
        int* dst = (int*)sh + (wv - 4) * 4096;
        #pragma unroll
        for (int i = 0; i < 4; ++i)
            #pragma unroll
            for (int j = 0; j < 4; ++j)
                #pragma unroll
                for (int g = 0; g < 4; ++g)
                    dst[((i * 4 + j) * 4 + g) * 64 + lane] = acc[i][j][g];
    }
    __syncthreads();

    int bsum = 0;
    if (wv < 4) {
        const float qs = 1.0f / (QSCALE * QSCALE);
        const int* src = (const int*)sh + wv * 4096;
        float* my = partials + (size_t)blockIdx.x * NB2;
        const int r0 = (lane >> 4) * 4;
        const int c0 = lane & 15;
        #pragma unroll
        for (int i = 0; i < 4; ++i)
            #pragma unroll
            for (int j = 0; j < 4; ++j)
                #pragma unroll
                for (int g = 0; g < 4; ++g) {
                    const int v = acc[i][j][g] + src[((i * 4 + j) * 4 + g) * 64 + lane];
                    bsum += v;
                    const int row = (rowQ + i) * 16 + r0 + g;
                    const int col = (colQ + j) * 16 + c0;
                    my[row * NBINS + col] = (float)v * qs;
                }
    }
    // block total (exact i32 within wave; f32 across waves is plenty)
    #pragma unroll
    for (int off = 32; off > 0; off >>= 1) bsum += __shfl_down(bsum, off, 64);
    if (lane == 0) xw[wv] = bsum;
    __syncthreads();
    if (tid == 0) {
        const float qs = 1.0f / (QSCALE * QSCALE);
        btot[blockIdx.x] = (float)(xw[0] + xw[1] + xw[2] + xw[3]) * qs;
    }
}

// level 1: 512 partials -> 16, float4-vectorized; grid (16, NGRP)
__global__ void reduceA_kernel(const float* __restrict__ partials,
                               float* __restrict__ partial2)
{
    const int bin4 = (blockIdx.x * 256 + threadIdx.x) * 4;
    const int g = blockIdx.y;
    const float4* p = (const float4*)(partials + (size_t)g * PPG * NB2 + bin4);
    float4 s = {0.f, 0.f, 0.f, 0.f};
    #pragma unroll
    for (int k = 0; k < PPG; ++k) {
        const float4 v = p[(size_t)k * (NB2 / 4)];
        s.x += v.x; s.y += v.y; s.z += v.z; s.w += v.w;
    }
    *(float4*)(partial2 + (size_t)g * NB2 + bin4) = s;
}

// fused level 2 + normalize: 16 -> 1, scale by 1/(total*dx*dy)
__global__ void scaleB_kernel(const float* __restrict__ partial2,
                              const float* __restrict__ btot,
                              const float* __restrict__ edges_x,
                              const float* __restrict__ edges_y,
                              float* __restrict__ out)
{
    __shared__ float ws[4];
    __shared__ float stot;

    float t = 0.0f;
    for (int i = threadIdx.x; i < NBLOCKS; i += 256) t += btot[i];
    #pragma unroll
    for (int off = 32; off > 0; off >>= 1) t += __shfl_down(t, off, 64);
    if ((threadIdx.x & 63) == 0) ws[threadIdx.x >> 6] = t;
    __syncthreads();
    if (threadIdx.x == 0) {
        const float dxw = edges_x[1] - edges_x[0];
        const float dyw = edges_y[1] - edges_y[0];
        stot = 1.0f / ((ws[0] + ws[1] + ws[2] + ws[3]) * dxw * dyw);
    }
    __syncthreads();

    const int bin = blockIdx.x * blockDim.x + threadIdx.x;
    float s = 0.0f;
    #pragma unroll
    for (int g = 0; g < NGRP; ++g) s += partial2[g * NB2 + bin];
    out[bin] = s * stot;
}

extern "C" void kernel_launch(void* const* d_in, const int* in_sizes, int n_in,
                              void* d_out, int out_size, void* d_ws, size_t ws_size,
                              hipStream_t stream)
{
    const float* x  = (const float*)d_in[0];
    const float* ex = (const float*)d_in[1];
    const float* ey = (const float*)d_in[2];
    float* out = (float*)d_out;
    const int n = in_sizes[0] / 6;

    float* partials = (float*)d_ws;                       // 512 * 16384
    float* partial2 = partials + (size_t)NBLOCKS * NB2;   // 16 * 16384
    float* btot     = partial2 + (size_t)NGRP * NB2;      // 512

    hist_mfma_kernel<<<NBLOCKS, THREADS, 0, stream>>>(x, ex, ey, partials, btot, n);
    reduceA_kernel<<<dim3(NB2 / 1024, NGRP), 256, 0, stream>>>(partials, partial2);
    scaleB_kernel<<<NB2 / 256, 256, 0, stream>>>(partial2, btot, ex, ey, out);
}